// Round 1
// baseline (2393.908 us; speedup 1.0000x reference)
//
#include <hip/hip_runtime.h>
#include <hip/hip_bf16.h>

// Swin window-attention block, fully fused, fp32.
// One block per (batch, window). B=32, C=192, H=W=56, win=7, heads=6, d=32.
// LDS plan (floats):
//   ys   [192][49]        @ 0      (persistent: BN'd depthwise output)
//   out  [192][49]        @ 9408   (attention output, all heads)
//   qs   [49][33]         @ 18816
//   ks   [49][33]         @ 20433
//   vs   [49][33]         @ 22050
//   wt   [32][193] / dots [49][49] @ 23667  (6176 floats, time-shared)
//   sc   [192]            @ 29843  (BN scale)
//   sh   [192]            @ 30035  (BN shift)
//   dwl  [192][9]         @ 30227  (depthwise weights)
//   total 31955 floats = 127,820 B -> 1 block/CU
//   xs [192][81] (x halo) aliases @ 9408..24960, phase-1 only.

#define TPB 512

#define YS_OFF   0
#define OUT_OFF  9408
#define QS_OFF   18816
#define KS_OFF   20433
#define VS_OFF   22050
#define WT_OFF   23667
#define SC_OFF   29843
#define SH_OFF   30035
#define DW_OFF   30227
#define SM_TOTAL 31955
#define XS_OFF   9408

__global__ __launch_bounds__(TPB)
void swin_fused_kernel(const float* __restrict__ x,
                       const float* __restrict__ mask,
                       const float* __restrict__ dw_w,
                       const float* __restrict__ bn_gamma,
                       const float* __restrict__ bn_beta,
                       const float* __restrict__ bn_mean,
                       const float* __restrict__ bn_var,
                       const float* __restrict__ pw_w,
                       const float* __restrict__ pw_b,
                       const float* __restrict__ proj_w,
                       const float* __restrict__ proj_b,
                       const float* __restrict__ rel_table,
                       float* __restrict__ out)
{
    __shared__ float sm[SM_TOTAL];
    const int t   = threadIdx.x;
    const int blk = blockIdx.x;
    const int b   = blk >> 6;        // batch
    const int wid = blk & 63;        // window id = wx*8 + wy
    const int wx  = wid >> 3, wy = wid & 7;
    const int X0  = wx * 7, Y0 = wy * 7;

    // ---- phase 0: BN coefficients + depthwise weights into LDS ----
    for (int c = t; c < 192; c += TPB) {
        float inv = bn_gamma[c] * rsqrtf(bn_var[c] + 1e-5f);
        sm[SC_OFF + c] = inv;
        sm[SH_OFF + c] = bn_beta[c] - bn_mean[c] * inv;
    }
    for (int i = t; i < 1728; i += TPB) sm[DW_OFF + i] = dw_w[i];

    // ---- phase 1a: stage x halo [192][9x9] with zero padding ----
    for (int idx = t; idx < 192 * 81; idx += TPB) {
        int c  = idx / 81, p = idx % 81;
        int di = p / 9,    dj = p % 9;
        int r  = X0 - 1 + di, cc = Y0 - 1 + dj;
        float v = 0.f;
        if (r >= 0 && r < 56 && cc >= 0 && cc < 56)
            v = x[((b * 192 + c) * 56 + r) * 56 + cc];
        sm[XS_OFF + idx] = v;
    }
    __syncthreads();

    // ---- phase 1b: depthwise 3x3 + BN -> ys[c][n] ----
    for (int idx = t; idx < 192 * 49; idx += TPB) {
        int c = idx / 49, n = idx % 49;
        int i = n / 7,    j = n % 7;
        const float* xc = &sm[XS_OFF + c * 81];
        const float* wc = &sm[DW_OFF + c * 9];
        float acc = 0.f;
#pragma unroll
        for (int dr = 0; dr < 3; ++dr)
#pragma unroll
            for (int ds = 0; ds < 3; ++ds)
                acc += xc[(i + dr) * 9 + (j + ds)] * wc[dr * 3 + ds];
        sm[YS_OFF + idx] = acc * sm[SC_OFF + c] + sm[SH_OFF + c];
    }
    __syncthreads();   // xs region now dead; qs/ks/vs/wt may reuse it

    const float scale = 1.0f / sqrtf(192.0f);   // dim_out^-0.5 (not head_dim)
    const int gdd = t & 15;      // dd0 = 2*gdd
    const int gn  = t >> 4;      // n0  = 2*gn, active if gn < 25
    const int n0  = gn * 2;
    const int dd0 = gdd * 2;

    // ---- phase 2: per-head qkv GEMM + attention ----
    for (int h = 0; h < 6; ++h) {
        for (int m = 0; m < 3; ++m) {           // 0=q 1=k 2=v
            const int o0 = m * 192 + h * 32;
            // stage weight tile [32 dd][192 c], pad stride 193
            for (int idx = t; idx < 32 * 192; idx += TPB) {
                int dd = idx / 192, c = idx % 192;
                sm[WT_OFF + dd * 193 + c] = pw_w[(o0 + dd) * 192 + c];
            }
            __syncthreads();
            float* dst = &sm[m == 0 ? QS_OFF : (m == 1 ? KS_OFF : VS_OFF)];
            if (gn < 25) {
                float a00 = 0.f, a01 = 0.f, a10 = 0.f, a11 = 0.f;
                const float* w0 = &sm[WT_OFF + dd0 * 193];
                const float* w1 = w0 + 193;
#pragma unroll 4
                for (int c = 0; c < 192; ++c) {
                    float ww0 = w0[c], ww1 = w1[c];
                    float y0  = sm[YS_OFF + c * 49 + n0];
                    float y1  = sm[YS_OFF + c * 49 + n0 + 1]; // n0=48: in-bounds garbage, discarded
                    a00 += ww0 * y0; a01 += ww0 * y1;
                    a10 += ww1 * y0; a11 += ww1 * y1;
                }
                float b0 = pw_b[o0 + dd0], b1 = pw_b[o0 + dd0 + 1];
                dst[n0 * 33 + dd0]     = a00 + b0;
                dst[n0 * 33 + dd0 + 1] = a10 + b1;
                if (n0 + 1 < 49) {
                    dst[(n0 + 1) * 33 + dd0]     = a01 + b0;
                    dst[(n0 + 1) * 33 + dd0 + 1] = a11 + b1;
                }
            }
            __syncthreads();
        }

        // dots[i][j] = scale*q.k + rel_bias + mask   (dots live in WT region)
        for (int idx = t; idx < 49 * 49; idx += TPB) {
            int i = idx / 49, j = idx % 49;
            const float* qrow = &sm[QS_OFF + i * 33];
            const float* krow = &sm[KS_OFF + j * 33];
            float acc = 0.f;
#pragma unroll 8
            for (int dd = 0; dd < 32; ++dd) acc += qrow[dd] * krow[dd];
            int a1 = i / 7, b1 = i % 7, a2 = j / 7, b2 = j % 7;
            int ridx = (a1 - a2 + 6) * 13 + (b1 - b2 + 6);
            float bias = rel_table[ridx * 6 + h];
            float mk   = mask[(wid * 49 + i) * 49 + j];
            sm[WT_OFF + idx] = acc * scale + bias + mk;
        }
        __syncthreads();

        // row softmax (49 rows, one thread each — tiny)
        if (t < 49) {
            float* row = &sm[WT_OFF + t * 49];
            float mx = -1e30f;
            for (int j = 0; j < 49; ++j) mx = fmaxf(mx, row[j]);
            float s = 0.f;
            for (int j = 0; j < 49; ++j) { float e = __expf(row[j] - mx); row[j] = e; s += e; }
            float r = 1.f / s;
            for (int j = 0; j < 49; ++j) row[j] *= r;
        }
        __syncthreads();

        // out[i][dd] = attn @ v  -> outacc[(h*32+dd)][i]
        for (int idx = t; idx < 49 * 32; idx += TPB) {
            int i = idx >> 5, dd = idx & 31;
            const float* arow = &sm[WT_OFF + i * 49];
            const float* vcol = &sm[VS_OFF + dd];
            float acc = 0.f;
#pragma unroll 7
            for (int j = 0; j < 49; ++j) acc += arow[j] * vcol[j * 33];
            sm[OUT_OFF + (h * 32 + dd) * 49 + i] = acc;
        }
        __syncthreads();
    }

    // ---- phase 3: fused proj GEMM -> global out ----
    for (int og = 0; og < 6; ++og) {
        for (int idx = t; idx < 32 * 192; idx += TPB) {
            int dd = idx / 192, c = idx % 192;
            sm[WT_OFF + dd * 193 + c] = proj_w[(og * 32 + dd) * 192 + c];
        }
        __syncthreads();
        if (gn < 25) {
            float a00 = 0.f, a01 = 0.f, a10 = 0.f, a11 = 0.f;
            const float* w0 = &sm[WT_OFF + dd0 * 193];
            const float* w1 = w0 + 193;
#pragma unroll 4
            for (int c = 0; c < 192; ++c) {
                float ww0 = w0[c], ww1 = w1[c];
                float y0  = sm[OUT_OFF + c * 49 + n0];
                float y1  = sm[OUT_OFF + c * 49 + n0 + 1]; // in-bounds garbage when n0=48, discarded
                a00 += ww0 * y0; a01 += ww0 * y1;
                a10 += ww1 * y0; a11 += ww1 * y1;
            }
            const int o_0 = og * 32 + dd0;
            {
                int i = n0 / 7, j = n0 % 7;
                int base = (b * 192) * 3136 + (X0 + i) * 56 + (Y0 + j);
                out[base + o_0 * 3136]       = a00 + proj_b[o_0];
                out[base + (o_0 + 1) * 3136] = a10 + proj_b[o_0 + 1];
            }
            if (n0 + 1 < 49) {
                int i = (n0 + 1) / 7, j = (n0 + 1) % 7;
                int base = (b * 192) * 3136 + (X0 + i) * 56 + (Y0 + j);
                out[base + o_0 * 3136]       = a01 + proj_b[o_0];
                out[base + (o_0 + 1) * 3136] = a11 + proj_b[o_0 + 1];
            }
        }
        __syncthreads();
    }
}

extern "C" void kernel_launch(void* const* d_in, const int* in_sizes, int n_in,
                              void* d_out, int out_size, void* d_ws, size_t ws_size,
                              hipStream_t stream) {
    const float* x         = (const float*)d_in[0];
    const float* mask      = (const float*)d_in[1];
    const float* dw_w      = (const float*)d_in[2];
    const float* bn_gamma  = (const float*)d_in[3];
    const float* bn_beta   = (const float*)d_in[4];
    const float* bn_mean   = (const float*)d_in[5];
    const float* bn_var    = (const float*)d_in[6];
    const float* pw_w      = (const float*)d_in[7];
    const float* pw_b      = (const float*)d_in[8];
    const float* proj_w    = (const float*)d_in[9];
    const float* proj_b    = (const float*)d_in[10];
    const float* rel_table = (const float*)d_in[11];
    float* outp            = (float*)d_out;

    dim3 grid(32 * 64);   // (batch, window)
    dim3 block(TPB);
    hipLaunchKernelGGL(swin_fused_kernel, grid, block, 0, stream,
                       x, mask, dw_w, bn_gamma, bn_beta, bn_mean, bn_var,
                       pw_w, pw_b, proj_w, proj_b, rel_table, outp);
}

// Round 2
// 616.689 us; speedup vs baseline: 3.8819x; 3.8819x over previous
//
#include <hip/hip_runtime.h>

// Swin window-attention block, fully fused, bf16-MFMA compute / fp32 accumulate.
// One block per (batch, window): 2048 blocks x 512 threads, 2 blocks/CU.
//
// LDS layout (bytes), total 76,480 (<80K -> 2 blocks/CU):
//   OT  @ 0      [52][200] bf16 20,800  attention output [n][c]  (proj B operand)
//   YT  @ 20800  [52][200] bf16 20,800  conv+BN output  [n][c]  (QKV B operand)
//   WA  @ 41600  [32][200] bf16 12,800  weight chunk    [o][c]  (A operand)
//        (aliased during attention: DOTS fp32 [49][52] + RS fp32[49])
//   QS  @ 54400  [52][40]  bf16  4,160  q  [i][dd]   (dots A)
//   KS  @ 58560  [52][40]  bf16  4,160  k  [j][dd]   (dots B, [n][k] layout)
//   VT  @ 62720  [32][72]  bf16  4,608  v  [dd][j]   (PV B,  [n][k] layout, j-pad zeroed)
//   E   @ 67328  [52][72]  bf16  7,488  exp(dots-m)  [i][j]  (PV A, j-pad zeroed)
//   PAD @ 74816  1,664  (absorbs E-region tile overreads)
// Phase-1 aliases: XS fp32[96][84] @ WA (spans WA..E, 32,256 B);
//                  DWL fp32[96][9] @ OT+0; SC fp32[192] @ OT+3456; SH @ OT+4224.
//
// MFMA mapping (m89-verified): mfma_f32_16x16x32_bf16(A,B,C):
//   A: lane holds A[row=lane&15][k0+8*(lane>>4) .. +7]   (row-major, k-contiguous)
//   B: lane holds B[k0+8*(lane>>4) .. +7][col=lane&15]   (stored [col][k], k-contiguous)
//   D: col=lane&15, row=4*(lane>>4)+reg
// All out-of-range (n>=49 / i>=49 / j>=49) tile lanes read in-bounds garbage and are
// discarded by write predicates; summation-axis pads (E cols, VT cols) are zeroed.

#define TPB 512

#define OT_B   0
#define YT_B   20800
#define WA_B   41600
#define QS_B   54400
#define KS_B   58560
#define VT_B   62720
#define E_B    67328
#define LDS_TOTAL 76480

#define DOTS_B WA_B
#define RS_B   (WA_B + 10192)
#define XS_B   WA_B
#define DWL_B  OT_B
#define SC_B   (OT_B + 3456)
#define SH_B   (OT_B + 4224)

typedef __attribute__((ext_vector_type(8))) short bf16x8;
typedef __attribute__((ext_vector_type(4))) float f32x4;

__device__ __forceinline__ unsigned short f2b(float f) {
    union { float f; unsigned u; } v; v.f = f;
    unsigned r = v.u + 0x7FFFu + ((v.u >> 16) & 1u);   // round-to-nearest-even
    return (unsigned short)(r >> 16);
}

__global__ __launch_bounds__(TPB, 4)
void swin_mfma_kernel(const float* __restrict__ x,
                      const float* __restrict__ mask,
                      const float* __restrict__ dw_w,
                      const float* __restrict__ bn_gamma,
                      const float* __restrict__ bn_beta,
                      const float* __restrict__ bn_mean,
                      const float* __restrict__ bn_var,
                      const float* __restrict__ pw_w,
                      const float* __restrict__ pw_b,
                      const float* __restrict__ proj_w,
                      const float* __restrict__ proj_b,
                      const float* __restrict__ rel_table,
                      float* __restrict__ out)
{
    __shared__ __align__(16) char lds[LDS_TOTAL];
    const int t    = threadIdx.x;
    const int blk  = blockIdx.x;
    const int b    = blk >> 6;
    const int wid  = blk & 63;
    const int X0   = (wid >> 3) * 7, Y0 = (wid & 7) * 7;
    const int lane = t & 63;
    const int w    = t >> 6;          // wave id 0..7
    const int col  = lane & 15;       // D col / A row / B col selector
    const int kg   = lane >> 4;       // k-group
    const float scale = 0.07216878364870323f;  // 192^-0.5

    // ---------------- phase 0: BN coefficients ----------------
    if (t < 192) {
        float inv = bn_gamma[t] * rsqrtf(bn_var[t] + 1e-5f);
        ((float*)(lds + SC_B))[t] = inv;
        ((float*)(lds + SH_B))[t] = bn_beta[t] - bn_mean[t] * inv;
    }

    // ---------------- phase 1: depthwise 3x3 + BN -> YT bf16 [n][c] ----------------
    for (int half = 0; half < 2; ++half) {
        const int c0 = half * 96;
        for (int idx = t; idx < 96 * 9; idx += TPB)
            ((float*)(lds + DWL_B))[idx] = dw_w[c0 * 9 + idx];
        for (int idx = t; idx < 96 * 81; idx += TPB) {
            int cl = idx / 81, p = idx - cl * 81;
            int di = p / 9, dj = p - di * 9;
            int r = X0 - 1 + di, cc = Y0 - 1 + dj;
            float v = 0.f;
            if ((unsigned)r < 56u && (unsigned)cc < 56u)
                v = x[((b * 192 + c0 + cl) * 56 + r) * 56 + cc];
            ((float*)(lds + XS_B))[cl * 84 + p] = v;
        }
        __syncthreads();
        for (int idx = t; idx < 96 * 49; idx += TPB) {
            int cl = idx / 49, n = idx - cl * 49;
            int i = n / 7, j = n - i * 7;
            const float* xc = (const float*)(lds + XS_B) + cl * 84;
            const float* wl = (const float*)(lds + DWL_B) + cl * 9;
            float acc = 0.f;
#pragma unroll
            for (int dr = 0; dr < 3; ++dr)
#pragma unroll
                for (int ds = 0; ds < 3; ++ds)
                    acc += xc[(i + dr) * 9 + (j + ds)] * wl[dr * 3 + ds];
            int c = c0 + cl;
            float yv = acc * ((float*)(lds + SC_B))[c] + ((float*)(lds + SH_B))[c];
            *(unsigned short*)(lds + YT_B + n * 400 + c * 2) = f2b(yv);
        }
        __syncthreads();
    }

    // ---------------- phase 2: per-head QKV GEMM + attention ----------------
    const int o_l = 16 * (w & 1);     // chunk-GEMM: 2 m-tiles
    const int n0g = 16 * (w >> 1);    // chunk-GEMM: 4 n-tiles

    for (int h = 0; h < 6; ++h) {
        // --- three 32-o weight chunks: q, k, v ---
#pragma unroll 1
        for (int m = 0; m < 3; ++m) {
            const int o_base = m * 192 + h * 32;
            const float* src = pw_w + o_base * 192;
            for (int idx = t; idx < 3072; idx += TPB) {      // stage [32][192] fp32 -> bf16
                int ol = idx / 96, c2 = idx - ol * 96;
                float2 v = *(const float2*)(src + ol * 192 + c2 * 2);
                unsigned p = ((unsigned)f2b(v.y) << 16) | (unsigned)f2b(v.x);
                *(unsigned*)(lds + WA_B + ol * 400 + c2 * 4) = p;
            }
            __syncthreads();
            {
                f32x4 acc = {0.f, 0.f, 0.f, 0.f};
                const char* aP = lds + WA_B + (o_l + col) * 400 + 16 * kg;
                const char* bP = lds + YT_B + (n0g + col) * 400 + 16 * kg;
#pragma unroll
                for (int kk = 0; kk < 6; ++kk) {
                    bf16x8 a  = *(const bf16x8*)(aP + 64 * kk);
                    bf16x8 bb = *(const bf16x8*)(bP + 64 * kk);
                    acc = __builtin_amdgcn_mfma_f32_16x16x32_bf16(a, bb, acc, 0, 0, 0);
                }
                const int n = n0g + col;                      // D col = window pos
#pragma unroll
                for (int reg = 0; reg < 4; ++reg) {
                    int od = o_l + 4 * kg + reg;              // D row = head-local channel
                    float val = acc[reg] + pw_b[o_base + od];
                    if (m == 2) {                             // v -> vt[dd][j], zero j-pad
                        *(unsigned short*)(lds + VT_B + od * 144 + n * 2) =
                            f2b(n < 49 ? val : 0.f);
                    } else if (n < 49) {                      // q,k -> [n][dd] transposed
                        int dst = (m == 0 ? QS_B : KS_B);
                        *(unsigned short*)(lds + dst + n * 80 + od * 2) = f2b(val);
                    }
                }
            }
            __syncthreads();
        }

        // --- dots = scale*(q k^T) + rel_bias + mask -> DOTS fp32 ---
        {
            const int i0 = 16 * (w & 3);
            const int jp = w >> 2;                            // 0/1
            bf16x8 a = *(const bf16x8*)(lds + QS_B + (i0 + col) * 80 + 16 * kg);
            f32x4 acc[2];
#pragma unroll
            for (int jt = 0; jt < 2; ++jt) {
                int j0 = 32 * jp + 16 * jt;
                bf16x8 bb = *(const bf16x8*)(lds + KS_B + (j0 + col) * 80 + 16 * kg);
                f32x4 z = {0.f, 0.f, 0.f, 0.f};
                acc[jt] = __builtin_amdgcn_mfma_f32_16x16x32_bf16(a, bb, z, 0, 0, 0);
            }
#pragma unroll
            for (int jt = 0; jt < 2; ++jt) {
                int j = 32 * jp + 16 * jt + col;
                if (j < 49) {
                    int aj = (j * 9363) >> 16, bj = j - aj * 7;
#pragma unroll
                    for (int reg = 0; reg < 4; ++reg) {
                        int i = i0 + 4 * kg + reg;
                        if (i < 49) {
                            int ai = (i * 9363) >> 16, bi = i - ai * 7;
                            int ridx = (ai - aj + 6) * 13 + (bi - bj + 6);
                            float val = acc[jt][reg] * scale
                                      + rel_table[ridx * 6 + h]
                                      + mask[wid * 2401 + i * 49 + j];
                            *(float*)(lds + DOTS_B + (i * 52 + j) * 4) = val;
                        }
                    }
                }
            }
        }
        __syncthreads();

        // --- softmax: 8 lanes per row, unnormalized exp -> E bf16, 1/sum -> RS ---
        if (t < 392) {
            const int r = t >> 3, j8 = t & 7;
            const float* drow = (const float*)(lds + DOTS_B) + r * 52;
            float mx = -3.4e38f;
            for (int j = j8; j < 49; j += 8) mx = fmaxf(mx, drow[j]);
            mx = fmaxf(mx, __shfl_xor(mx, 1));
            mx = fmaxf(mx, __shfl_xor(mx, 2));
            mx = fmaxf(mx, __shfl_xor(mx, 4));
            float s = 0.f;
            for (int j = j8; j < 49; j += 8) {
                float e = __expf(drow[j] - mx);
                s += e;
                *(unsigned short*)(lds + E_B + r * 144 + j * 2) = f2b(e);
            }
            // zero K-pad cols 49..63
            *(unsigned short*)(lds + E_B + r * 144 + (49 + j8) * 2) = 0;
            if (57 + j8 < 64)
                *(unsigned short*)(lds + E_B + r * 144 + (57 + j8) * 2) = 0;
            s += __shfl_xor(s, 1);
            s += __shfl_xor(s, 2);
            s += __shfl_xor(s, 4);
            if (j8 == 0) ((float*)(lds + RS_B))[r] = 1.f / s;
        }
        __syncthreads();

        // --- PV: out[i][dd] = (e @ v) * rs[i] -> OT bf16 [n][c] ---
        {
            const int i0  = 16 * (w & 3);
            const int dd0 = 16 * (w >> 2);                    // 0/16
            f32x4 acc = {0.f, 0.f, 0.f, 0.f};
#pragma unroll
            for (int kk = 0; kk < 2; ++kk) {
                bf16x8 a  = *(const bf16x8*)(lds + E_B  + (i0 + col) * 144 + 64 * kk + 16 * kg);
                bf16x8 bb = *(const bf16x8*)(lds + VT_B + (dd0 + col) * 144 + 64 * kk + 16 * kg);
                acc = __builtin_amdgcn_mfma_f32_16x16x32_bf16(a, bb, acc, 0, 0, 0);
            }
            const int dd = dd0 + col;
#pragma unroll
            for (int reg = 0; reg < 4; ++reg) {
                int i = i0 + 4 * kg + reg;
                if (i < 49) {
                    float val = acc[reg] * ((const float*)(lds + RS_B))[i];
                    *(unsigned short*)(lds + OT_B + i * 400 + (h * 32 + dd) * 2) = f2b(val);
                }
            }
        }
        __syncthreads();
    }

    // ---------------- phase 3: proj GEMM -> global out ----------------
#pragma unroll 1
    for (int og = 0; og < 6; ++og) {
        const float* src = proj_w + og * 32 * 192;
        for (int idx = t; idx < 3072; idx += TPB) {
            int ol = idx / 96, c2 = idx - ol * 96;
            float2 v = *(const float2*)(src + ol * 192 + c2 * 2);
            unsigned p = ((unsigned)f2b(v.y) << 16) | (unsigned)f2b(v.x);
            *(unsigned*)(lds + WA_B + ol * 400 + c2 * 4) = p;
        }
        __syncthreads();
        {
            f32x4 acc = {0.f, 0.f, 0.f, 0.f};
            const char* aP = lds + WA_B + (o_l + col) * 400 + 16 * kg;
            const char* bP = lds + OT_B + (n0g + col) * 400 + 16 * kg;
#pragma unroll
            for (int kk = 0; kk < 6; ++kk) {
                bf16x8 a  = *(const bf16x8*)(aP + 64 * kk);
                bf16x8 bb = *(const bf16x8*)(bP + 64 * kk);
                acc = __builtin_amdgcn_mfma_f32_16x16x32_bf16(a, bb, acc, 0, 0, 0);
            }
            const int n = n0g + col;
            if (n < 49) {
                int i = n / 7, j = n - i * 7;
                long base = ((long)(b * 192) * 3136) + (X0 + i) * 56 + (Y0 + j);
#pragma unroll
                for (int reg = 0; reg < 4; ++reg) {
                    int o = og * 32 + o_l + 4 * kg + reg;
                    out[base + (long)o * 3136] = acc[reg] + proj_b[o];
                }
            }
        }
        __syncthreads();
    }
}

extern "C" void kernel_launch(void* const* d_in, const int* in_sizes, int n_in,
                              void* d_out, int out_size, void* d_ws, size_t ws_size,
                              hipStream_t stream) {
    const float* x         = (const float*)d_in[0];
    const float* mask      = (const float*)d_in[1];
    const float* dw_w      = (const float*)d_in[2];
    const float* bn_gamma  = (const float*)d_in[3];
    const float* bn_beta   = (const float*)d_in[4];
    const float* bn_mean   = (const float*)d_in[5];
    const float* bn_var    = (const float*)d_in[6];
    const float* pw_w      = (const float*)d_in[7];
    const float* pw_b      = (const float*)d_in[8];
    const float* proj_w    = (const float*)d_in[9];
    const float* proj_b    = (const float*)d_in[10];
    const float* rel_table = (const float*)d_in[11];
    float* outp            = (float*)d_out;

    hipLaunchKernelGGL(swin_mfma_kernel, dim3(32 * 64), dim3(TPB), 0, stream,
                       x, mask, dw_w, bn_gamma, bn_beta, bn_mean, bn_var,
                       pw_w, pw_b, proj_w, proj_b, rel_table, outp);
}

// Round 7
// 377.292 us; speedup vs baseline: 6.3450x; 1.6345x over previous
//
#include <hip/hip_runtime.h>

// Swin window-attention block — 5-kernel pipeline (bf16 MFMA), with fused
// single-kernel fallback when ws_size is insufficient.
//
// ws layout (bytes):
//   Y    @ 0           bf16 [100352][192]   38,535,168
//   QKV  @ 38,535,168  bf16 [100352][576]  115,605,504
//   ATT  @ 154,140,672 bf16 [100352][192]   38,535,168
//   WQ   @ 192,675,840 bf16 [576][192]         221,184
//   WP   @ 192,897,024 bf16 [192][192]          73,728
//   NEED = 192,970,752

typedef __attribute__((ext_vector_type(8))) short bf16x8;
typedef __attribute__((ext_vector_type(4))) float f32x4;
typedef unsigned int uint32;

__device__ __forceinline__ unsigned short f2b(float f) {
    union { float f; unsigned u; } v; v.f = f;
    unsigned r = v.u + 0x7FFFu + ((v.u >> 16) & 1u);   // RNE
    return (unsigned short)(r >> 16);
}

__device__ __forceinline__ void gload_lds16(const void* g, void* l) {
    __builtin_amdgcn_global_load_lds(
        (const __attribute__((address_space(1))) uint32*)g,
        (__attribute__((address_space(3))) uint32*)l, 16, 0, 0);
}

// ---------------- K0: weight fp32 -> bf16 ----------------
__global__ __launch_bounds__(256)
void k0_convert(const float* __restrict__ pw_w, const float* __restrict__ proj_w,
                unsigned* __restrict__ wq, unsigned* __restrict__ wp)
{
    int i = blockIdx.x * 256 + threadIdx.x;              // 73,728 total
    if (i < 55296) {
        float2 v = *(const float2*)(pw_w + 2 * i);
        wq[i] = (unsigned)f2b(v.x) | ((unsigned)f2b(v.y) << 16);
    } else {
        int j = i - 55296;
        float2 v = *(const float2*)(proj_w + 2 * j);
        wp[j] = (unsigned)f2b(v.x) | ((unsigned)f2b(v.y) << 16);
    }
}

// ---------------- K1: depthwise 3x3 + BN -> y[p][192] bf16 ----------------
#define K1S 61
__global__ __launch_bounds__(256)
void k1_dwconv(const float* __restrict__ x, const float* __restrict__ dw_w,
               const float* __restrict__ bn_gamma, const float* __restrict__ bn_beta,
               const float* __restrict__ bn_mean, const float* __restrict__ bn_var,
               unsigned* __restrict__ y)                  // bf16 pairs [p][96]
{
    __shared__ float xs[64 * 3 * K1S];                    // [cl][rr][jj], jj=cc+1
    const int t = threadIdx.x;
    const int b = blockIdx.x / 56, r = blockIdx.x - (blockIdx.x / 56) * 56;
    const int cp = t & 31, cl0 = 2 * cp;

    for (int ch = 0; ch < 3; ++ch) {
        const int c0 = ch * 64;
        for (int it = 0; it < 11; ++it) {
            int item = t + 256 * it;
            if (item < 2688) {                            // 64cl * 3rr * 14(i4)
                int cl = item / 42, rem = item - cl * 42;
                int rr = rem / 14, i4 = rem - rr * 14;
                int r2 = r + rr - 1;
                float4 v = make_float4(0.f, 0.f, 0.f, 0.f);
                if ((unsigned)r2 < 56u)
                    v = *(const float4*)(x + ((b * 192 + c0 + cl) * 56 + r2) * 56 + 4 * i4);
                float* dst = &xs[(cl * 3 + rr) * K1S + 1 + 4 * i4];
                dst[0] = v.x; dst[1] = v.y; dst[2] = v.z; dst[3] = v.w;
            }
        }
        if (t < 192) {
            int cl = t / 3, rr = t - (t / 3) * 3;
            xs[(cl * 3 + rr) * K1S + 0] = 0.f;
            xs[(cl * 3 + rr) * K1S + 57] = 0.f;
        }
        __syncthreads();
        const int cA = c0 + cl0, cB = cA + 1;
        float invA = bn_gamma[cA] * rsqrtf(bn_var[cA] + 1e-5f);
        float shA  = bn_beta[cA] - bn_mean[cA] * invA;
        float invB = bn_gamma[cB] * rsqrtf(bn_var[cB] + 1e-5f);
        float shB  = bn_beta[cB] - bn_mean[cB] * invB;
        float wA[9], wB[9];
#pragma unroll
        for (int q = 0; q < 9; ++q) { wA[q] = dw_w[cA * 9 + q]; wB[q] = dw_w[cB * 9 + q]; }
        const float* xa = &xs[(cl0 * 3) * K1S];
        const float* xb = &xs[((cl0 + 1) * 3) * K1S];
        for (int it = 0; it < 7; ++it) {
            int cc = (t >> 5) + 8 * it;
            float a0 = 0.f, a1 = 0.f;
#pragma unroll
            for (int dr = 0; dr < 3; ++dr)
#pragma unroll
                for (int dc = 0; dc < 3; ++dc) {
                    a0 += xa[dr * K1S + cc + dc] * wA[dr * 3 + dc];
                    a1 += xb[dr * K1S + cc + dc] * wB[dr * 3 + dc];
                }
            float y0 = a0 * invA + shA, y1 = a1 * invB + shB;
            int p = b * 3136 + r * 56 + cc;
            y[p * 96 + 32 * ch + cp] = (unsigned)f2b(y0) | ((unsigned)f2b(y1) << 16);
        }
        __syncthreads();
    }
}

// ---------------- K2: QKV GEMM [128p x 192o-loop x K192] ----------------
__global__ __launch_bounds__(512, 4)
void k2_qkv(const char* __restrict__ yb, const char* __restrict__ wqb,
            const float* __restrict__ pw_b, char* __restrict__ qkvb)
{
    __shared__ __align__(16) char lds[73728];             // A[128][192] @0, B[64][192] @49152
    int bid = blockIdx.x;
    bid = (bid & 7) * 294 + (bid >> 3);                   // XCD swizzle (2352 = 8*294)
    const int pt = bid / 3, og = bid - (bid / 3) * 3;
    const int p0 = pt * 128;
    const int t = threadIdx.x, lane = t & 63, w = t >> 6;
    const int col = lane & 15, kg = lane >> 4;

    auto stageB = [&](int ot) {
        const char* gB = wqb + (size_t)(ot * 64) * 384;
#pragma unroll
        for (int it = 0; it < 3; ++it) {
            int dl = it * 8192 + w * 1024 + lane * 16;
            int i = dl / 384, c = dl - i * 384;
            gload_lds16(gB + i * 384 + (c ^ ((i & 7) << 4)), lds + 49152 + dl);
        }
    };
    {   // stage A (y rows p0..p0+127) with pre-swizzled source
        const char* gA = yb + (size_t)p0 * 384;
#pragma unroll
        for (int it = 0; it < 6; ++it) {
            int dl = it * 8192 + w * 1024 + lane * 16;
            int i = dl / 384, c = dl - i * 384;
            gload_lds16(gA + i * 384 + (c ^ ((i & 7) << 4)), lds + dl);
        }
        stageB(og * 3);
    }
    __syncthreads();

    const int wp = w & 3, wo = w >> 2;
    const f32x4 zz = {0.f, 0.f, 0.f, 0.f};
    for (int k = 0; k < 3; ++k) {
        const int ot = og * 3 + k;
        f32x4 acc[2][2];
        acc[0][0] = zz; acc[0][1] = zz; acc[1][0] = zz; acc[1][1] = zz;
#pragma unroll
        for (int kk = 0; kk < 6; ++kk) {
            const int c = 16 * kg + 64 * kk;
            bf16x8 a[2], bb[2];
#pragma unroll
            for (int mt = 0; mt < 2; ++mt) {
                int row = 32 * wp + 16 * mt + col;
                a[mt] = *(const bf16x8*)(lds + row * 384 + (c ^ ((row & 7) << 4)));
            }
#pragma unroll
            for (int nt = 0; nt < 2; ++nt) {
                int row = 32 * wo + 16 * nt + col;
                bb[nt] = *(const bf16x8*)(lds + 49152 + row * 384 + (c ^ ((row & 7) << 4)));
            }
#pragma unroll
            for (int mt = 0; mt < 2; ++mt)
#pragma unroll
                for (int nt = 0; nt < 2; ++nt)
                    acc[mt][nt] = __builtin_amdgcn_mfma_f32_16x16x32_bf16(a[mt], bb[nt], acc[mt][nt], 0, 0, 0);
        }
#pragma unroll
        for (int nt = 0; nt < 2; ++nt) {
            int o_g = ot * 64 + 32 * wo + 16 * nt + col;
            float pb = pw_b[o_g];
#pragma unroll
            for (int mt = 0; mt < 2; ++mt)
#pragma unroll
                for (int reg = 0; reg < 4; ++reg) {
                    int p_g = p0 + 32 * wp + 16 * mt + 4 * kg + reg;
                    *(unsigned short*)(qkvb + ((size_t)p_g * 576 + o_g) * 2) =
                        f2b(acc[mt][nt][reg] + pb);
                }
        }
        if (k < 2) {
            __syncthreads();
            stageB(ot + 1);
            __syncthreads();
        }
    }
}

// ---------------- K3: windowed attention (6 heads) ----------------
#define QB3    0
#define KB3    19600
#define VTB3   39200
#define EB3    63776
#define DOTS3  70832
#define RS3    81024
#define K3LDS  81220
__global__ __launch_bounds__(512, 4)
void k3_attn(const char* __restrict__ qkvb, const float* __restrict__ mask,
             const float* __restrict__ rel_table, char* __restrict__ attb)
{
    __shared__ __align__(16) char lds[K3LDS];
    const int t = threadIdx.x, lane = t & 63, w = t >> 6;
    const int col = lane & 15, kg = lane >> 4;
    const int b = blockIdx.x >> 6, wid = blockIdx.x & 63;
    const int X0 = (wid >> 3) * 7, Y0 = (wid & 7) * 7;
    const float scale = 0.07216878364870323f;             // 192^-0.5

    auto PIX = [&](int n) { int rr = n / 7; return b * 3136 + (X0 + rr) * 56 + Y0 + (n - rr * 7); };

    // stage Q [49][200ch], K [49][200ch] (stride 400 B)
#pragma unroll
    for (int it = 0; it < 3; ++it) {
        int item = t + 512 * it;
        if (item < 1176) {
            int r = item / 24, c8 = item - r * 24;
            size_t gb = (size_t)PIX(r) * 1152 + 16 * c8;
            *(bf16x8*)(lds + QB3 + r * 400 + 16 * c8) = *(const bf16x8*)(qkvb + gb);
            *(bf16x8*)(lds + KB3 + r * 400 + 16 * c8) = *(const bf16x8*)(qkvb + gb + 384);
        }
    }
    // stage V transposed: VT[192 dd][64 j] (stride 128 B, XOR-swizzled)
#pragma unroll
    for (int it = 0; it < 3; ++it) {
        int item = t + 512 * it;
        if (item < 1176) {
            int j = item / 24, dd8 = item - j * 24;
            bf16x8 v = *(const bf16x8*)(qkvb + (size_t)PIX(j) * 1152 + 768 + 16 * dd8);
            int sw = (dd8 & 7) << 4;
#pragma unroll
            for (int i = 0; i < 8; ++i)
                *(unsigned short*)(lds + VTB3 + (8 * dd8 + i) * 128 + ((2 * j) ^ sw)) =
                    (unsigned short)v[i];
        }
    }
    // zero VT j-pad 49..63
#pragma unroll
    for (int it = 0; it < 6; ++it) {
        int item = t + 512 * it;
        if (item < 2880) {
            int row = item / 15, jz = 49 + (item - (item / 15) * 15);
            *(unsigned short*)(lds + VTB3 + row * 128 + ((2 * jz) ^ (((row >> 3) & 7) << 4))) = 0;
        }
    }
    __syncthreads();

    const int jt = w & 3, ih = w >> 2;                    // dots wave mapping
    const int dd0 = 16 * (w & 1), i0p = 16 * (w >> 1);    // PV wave mapping
    const f32x4 zz = {0.f, 0.f, 0.f, 0.f};

    for (int h = 0; h < 6; ++h) {
        // ---- dots: D[j][i] = K x Q -> DOTS[i][j] raw (float4 writes) ----
        {
            const int j0 = 16 * jt;
            bf16x8 a = *(const bf16x8*)(lds + KB3 + (j0 + col) * 400 + 64 * h + 16 * kg);
#pragma unroll
            for (int q = 0; q < 2; ++q) {
                int i0 = 32 * ih + 16 * q;
                bf16x8 bb = *(const bf16x8*)(lds + QB3 + (i0 + col) * 400 + 64 * h + 16 * kg);
                f32x4 d4 = __builtin_amdgcn_mfma_f32_16x16x32_bf16(a, bb, zz, 0, 0, 0);
                int i = i0 + col, jb = j0 + 4 * kg;
                if (i < 49 && jb <= 48)
                    *(f32x4*)(lds + DOTS3 + (i * 52 + jb) * 4) = d4;
            }
        }
        __syncthreads();
        // ---- softmax (scale+bias+mask fused), E bf16 [49][72ch], RS=1/sum ----
        if (t < 392) {
            int r = t >> 3, j8 = t & 7;
            float* drow = (float*)(lds + DOTS3) + r * 52;
            int ar = r / 7, br = r - ar * 7;
            const float* mrow = mask + wid * 2401 + r * 49;
            float mx = -3.4e38f;
            for (int j = j8; j < 49; j += 8) {
                int aj = j / 7, bj = j - aj * 7;
                float val = drow[j] * scale
                          + rel_table[((ar - aj + 6) * 13 + (br - bj + 6)) * 6 + h]
                          + mrow[j];
                drow[j] = val;
                mx = fmaxf(mx, val);
            }
            mx = fmaxf(mx, __shfl_xor(mx, 1));
            mx = fmaxf(mx, __shfl_xor(mx, 2));
            mx = fmaxf(mx, __shfl_xor(mx, 4));
            float s = 0.f;
            for (int j = j8; j < 49; j += 8) {
                float e = __expf(drow[j] - mx);
                s += e;
                *(unsigned short*)(lds + EB3 + r * 144 + 2 * j) = f2b(e);
            }
            *(unsigned short*)(lds + EB3 + r * 144 + 2 * (49 + j8)) = 0;
            if (57 + j8 < 64)
                *(unsigned short*)(lds + EB3 + r * 144 + 2 * (57 + j8)) = 0;
            s += __shfl_xor(s, 1);
            s += __shfl_xor(s, 2);
            s += __shfl_xor(s, 4);
            if (j8 == 0) ((float*)(lds + RS3))[r] = 1.f / s;
        }
        __syncthreads();
        // ---- PV: D[dd][i] = VT x E ; packed 8-B stores ----
        {
            f32x4 acc = zz;
            const int ddg = h * 32 + dd0 + col;
#pragma unroll
            for (int kk = 0; kk < 2; ++kk) {
                bf16x8 a = *(const bf16x8*)(lds + VTB3 + ddg * 128 +
                               ((16 * kg + 64 * kk) ^ (((ddg >> 3) & 7) << 4)));
                bf16x8 bb = *(const bf16x8*)(lds + EB3 + (i0p + col) * 144 + 16 * kg + 64 * kk);
                acc = __builtin_amdgcn_mfma_f32_16x16x32_bf16(a, bb, acc, 0, 0, 0);
            }
            int i = i0p + col;
            if (i < 49) {
                float rs = ((const float*)(lds + RS3))[i];
                unsigned u0 = (unsigned)f2b(acc[0] * rs) | ((unsigned)f2b(acc[1] * rs) << 16);
                unsigned u1 = (unsigned)f2b(acc[2] * rs) | ((unsigned)f2b(acc[3] * rs) << 16);
                *(uint2*)(attb + ((size_t)PIX(i) * 192 + h * 32 + dd0 + 4 * kg) * 2) =
                    make_uint2(u0, u1);
            }
        }
        // no barrier needed here (DOTS region disjoint from E/RS; post-dots
        // barrier orders all PV reads of E before softmax overwrites it)
    }
}

// ---------------- K4: proj GEMM -> fp32 NCHW out ----------------
__global__ __launch_bounds__(512, 4)
void k4_proj(const char* __restrict__ attb, const char* __restrict__ wpb,
             const float* __restrict__ proj_b, float* __restrict__ outp)
{
    __shared__ __align__(16) char lds[73728];             // W[64][192] @0, X[128][192] @24576
    int bid = blockIdx.x;
    bid = (bid & 7) * 294 + (bid >> 3);                   // 2352 = 8*294
    const int pt = bid / 3, ot = bid - (bid / 3) * 3;
    const int p0 = pt * 128, o0 = ot * 64;
    const int t = threadIdx.x, lane = t & 63, w = t >> 6;
    const int col = lane & 15, kg = lane >> 4;

    {
        const char* gW = wpb + (size_t)o0 * 384;
        const char* gX = attb + (size_t)p0 * 384;
#pragma unroll
        for (int it = 0; it < 9; ++it) {
            int d = it * 8192 + w * 1024 + lane * 16;
            int dl = (it < 3) ? d : d - 24576;
            const char* gb = (it < 3) ? gW : gX;
            int i = dl / 384, c = dl - i * 384;
            gload_lds16(gb + i * 384 + (c ^ ((i & 7) << 4)), lds + d);
        }
    }
    __syncthreads();

    const int wo = w & 1, wp4 = w >> 1;
    const f32x4 zz = {0.f, 0.f, 0.f, 0.f};
    f32x4 acc[2][2];
    acc[0][0] = zz; acc[0][1] = zz; acc[1][0] = zz; acc[1][1] = zz;
#pragma unroll
    for (int kk = 0; kk < 6; ++kk) {
        const int c = 16 * kg + 64 * kk;
        bf16x8 a[2], bb[2];
#pragma unroll
        for (int mt = 0; mt < 2; ++mt) {
            int row = 32 * wo + 16 * mt + col;
            a[mt] = *(const bf16x8*)(lds + row * 384 + (c ^ ((row & 7) << 4)));
        }
#pragma unroll
        for (int nt = 0; nt < 2; ++nt) {
            int row = 32 * wp4 + 16 * nt + col;
            bb[nt] = *(const bf16x8*)(lds + 24576 + row * 384 + (c ^ ((row & 7) << 4)));
        }
#pragma unroll
        for (int mt = 0; mt < 2; ++mt)
#pragma unroll
            for (int nt = 0; nt < 2; ++nt)
                acc[mt][nt] = __builtin_amdgcn_mfma_f32_16x16x32_bf16(a[mt], bb[nt], acc[mt][nt], 0, 0, 0);
    }
#pragma unroll
    for (int nt = 0; nt < 2; ++nt) {
        int p_g = p0 + 32 * wp4 + 16 * nt + col;
        int bg = p_g / 3136, hw = p_g - bg * 3136;
#pragma unroll
        for (int mt = 0; mt < 2; ++mt)
#pragma unroll
            for (int reg = 0; reg < 4; ++reg) {
                int o_g = o0 + 32 * wo + 16 * mt + 4 * kg + reg;
                outp[(size_t)(bg * 192 + o_g) * 3136 + hw] = acc[mt][nt][reg] + proj_b[o_g];
            }
    }
}

// ================= fallback: round-2 fused kernel (passes, 617 us) =================
#define TPB 512
#define OT_B   0
#define YT_B   20800
#define WA_B   41600
#define QS_B   54400
#define KS_B   58560
#define VT_B   62720
#define E_B    67328
#define LDS_TOTAL 76480
#define DOTS_B WA_B
#define RS_B   (WA_B + 10192)
#define XS_B   WA_B
#define DWL_B  OT_B
#define SC_B   (OT_B + 3456)
#define SH_B   (OT_B + 4224)

__global__ __launch_bounds__(TPB, 4)
void swin_mfma_kernel(const float* __restrict__ x,
                      const float* __restrict__ mask,
                      const float* __restrict__ dw_w,
                      const float* __restrict__ bn_gamma,
                      const float* __restrict__ bn_beta,
                      const float* __restrict__ bn_mean,
                      const float* __restrict__ bn_var,
                      const float* __restrict__ pw_w,
                      const float* __restrict__ pw_b,
                      const float* __restrict__ proj_w,
                      const float* __restrict__ proj_b,
                      const float* __restrict__ rel_table,
                      float* __restrict__ out)
{
    __shared__ __align__(16) char lds[LDS_TOTAL];
    const int t    = threadIdx.x;
    const int blk  = blockIdx.x;
    const int b    = blk >> 6;
    const int wid  = blk & 63;
    const int X0   = (wid >> 3) * 7, Y0 = (wid & 7) * 7;
    const int lane = t & 63;
    const int w    = t >> 6;
    const int col  = lane & 15;
    const int kg   = lane >> 4;
    const float scale = 0.07216878364870323f;

    if (t < 192) {
        float inv = bn_gamma[t] * rsqrtf(bn_var[t] + 1e-5f);
        ((float*)(lds + SC_B))[t] = inv;
        ((float*)(lds + SH_B))[t] = bn_beta[t] - bn_mean[t] * inv;
    }
    for (int half = 0; half < 2; ++half) {
        const int c0 = half * 96;
        for (int idx = t; idx < 96 * 9; idx += TPB)
            ((float*)(lds + DWL_B))[idx] = dw_w[c0 * 9 + idx];
        for (int idx = t; idx < 96 * 81; idx += TPB) {
            int cl = idx / 81, p = idx - cl * 81;
            int di = p / 9, dj = p - di * 9;
            int r = X0 - 1 + di, cc = Y0 - 1 + dj;
            float v = 0.f;
            if ((unsigned)r < 56u && (unsigned)cc < 56u)
                v = x[((b * 192 + c0 + cl) * 56 + r) * 56 + cc];
            ((float*)(lds + XS_B))[cl * 84 + p] = v;
        }
        __syncthreads();
        for (int idx = t; idx < 96 * 49; idx += TPB) {
            int cl = idx / 49, n = idx - cl * 49;
            int i = n / 7, j = n - i * 7;
            const float* xc = (const float*)(lds + XS_B) + cl * 84;
            const float* wl = (const float*)(lds + DWL_B) + cl * 9;
            float acc = 0.f;
#pragma unroll
            for (int dr = 0; dr < 3; ++dr)
#pragma unroll
                for (int ds = 0; ds < 3; ++ds)
                    acc += xc[(i + dr) * 9 + (j + ds)] * wl[dr * 3 + ds];
            int c = c0 + cl;
            float yv = acc * ((float*)(lds + SC_B))[c] + ((float*)(lds + SH_B))[c];
            *(unsigned short*)(lds + YT_B + n * 400 + c * 2) = f2b(yv);
        }
        __syncthreads();
    }
    const int o_l = 16 * (w & 1);
    const int n0g = 16 * (w >> 1);
    for (int h = 0; h < 6; ++h) {
#pragma unroll 1
        for (int m = 0; m < 3; ++m) {
            const int o_base = m * 192 + h * 32;
            const float* src = pw_w + o_base * 192;
            for (int idx = t; idx < 3072; idx += TPB) {
                int ol = idx / 96, c2 = idx - ol * 96;
                float2 v = *(const float2*)(src + ol * 192 + c2 * 2);
                unsigned p = ((unsigned)f2b(v.y) << 16) | (unsigned)f2b(v.x);
                *(unsigned*)(lds + WA_B + ol * 400 + c2 * 4) = p;
            }
            __syncthreads();
            {
                f32x4 acc = {0.f, 0.f, 0.f, 0.f};
                const char* aP = lds + WA_B + (o_l + col) * 400 + 16 * kg;
                const char* bP = lds + YT_B + (n0g + col) * 400 + 16 * kg;
#pragma unroll
                for (int kk = 0; kk < 6; ++kk) {
                    bf16x8 a  = *(const bf16x8*)(aP + 64 * kk);
                    bf16x8 bb = *(const bf16x8*)(bP + 64 * kk);
                    acc = __builtin_amdgcn_mfma_f32_16x16x32_bf16(a, bb, acc, 0, 0, 0);
                }
                const int n = n0g + col;
#pragma unroll
                for (int reg = 0; reg < 4; ++reg) {
                    int od = o_l + 4 * kg + reg;
                    float val = acc[reg] + pw_b[o_base + od];
                    if (m == 2) {
                        *(unsigned short*)(lds + VT_B + od * 144 + n * 2) =
                            f2b(n < 49 ? val : 0.f);
                    } else if (n < 49) {
                        int dst = (m == 0 ? QS_B : KS_B);
                        *(unsigned short*)(lds + dst + n * 80 + od * 2) = f2b(val);
                    }
                }
            }
            __syncthreads();
        }
        {
            const int i0 = 16 * (w & 3);
            const int jp = w >> 2;
            bf16x8 a = *(const bf16x8*)(lds + QS_B + (i0 + col) * 80 + 16 * kg);
            f32x4 acc[2];
#pragma unroll
            for (int jt = 0; jt < 2; ++jt) {
                int j0 = 32 * jp + 16 * jt;
                bf16x8 bb = *(const bf16x8*)(lds + KS_B + (j0 + col) * 80 + 16 * kg);
                f32x4 z = {0.f, 0.f, 0.f, 0.f};
                acc[jt] = __builtin_amdgcn_mfma_f32_16x16x32_bf16(a, bb, z, 0, 0, 0);
            }
#pragma unroll
            for (int jt = 0; jt < 2; ++jt) {
                int j = 32 * jp + 16 * jt + col;
                if (j < 49) {
                    int aj = (j * 9363) >> 16, bj = j - aj * 7;
#pragma unroll
                    for (int reg = 0; reg < 4; ++reg) {
                        int i = i0 + 4 * kg + reg;
                        if (i < 49) {
                            int ai = (i * 9363) >> 16, bi = i - ai * 7;
                            int ridx = (ai - aj + 6) * 13 + (bi - bj + 6);
                            float val = acc[jt][reg] * scale
                                      + rel_table[ridx * 6 + h]
                                      + mask[wid * 2401 + i * 49 + j];
                            *(float*)(lds + DOTS_B + (i * 52 + j) * 4) = val;
                        }
                    }
                }
            }
        }
        __syncthreads();
        if (t < 392) {
            const int r = t >> 3, j8 = t & 7;
            const float* drow = (const float*)(lds + DOTS_B) + r * 52;
            float mx = -3.4e38f;
            for (int j = j8; j < 49; j += 8) mx = fmaxf(mx, drow[j]);
            mx = fmaxf(mx, __shfl_xor(mx, 1));
            mx = fmaxf(mx, __shfl_xor(mx, 2));
            mx = fmaxf(mx, __shfl_xor(mx, 4));
            float s = 0.f;
            for (int j = j8; j < 49; j += 8) {
                float e = __expf(drow[j] - mx);
                s += e;
                *(unsigned short*)(lds + E_B + r * 144 + j * 2) = f2b(e);
            }
            *(unsigned short*)(lds + E_B + r * 144 + (49 + j8) * 2) = 0;
            if (57 + j8 < 64)
                *(unsigned short*)(lds + E_B + r * 144 + (57 + j8) * 2) = 0;
            s += __shfl_xor(s, 1);
            s += __shfl_xor(s, 2);
            s += __shfl_xor(s, 4);
            if (j8 == 0) ((float*)(lds + RS_B))[r] = 1.f / s;
        }
        __syncthreads();
        {
            const int i0  = 16 * (w & 3);
            const int dd0 = 16 * (w >> 2);
            f32x4 acc = {0.f, 0.f, 0.f, 0.f};
#pragma unroll
            for (int kk = 0; kk < 2; ++kk) {
                bf16x8 a  = *(const bf16x8*)(lds + E_B  + (i0 + col) * 144 + 64 * kk + 16 * kg);
                bf16x8 bb = *(const bf16x8*)(lds + VT_B + (dd0 + col) * 144 + 64 * kk + 16 * kg);
                acc = __builtin_amdgcn_mfma_f32_16x16x32_bf16(a, bb, acc, 0, 0, 0);
            }
            const int dd = dd0 + col;
#pragma unroll
            for (int reg = 0; reg < 4; ++reg) {
                int i = i0 + 4 * kg + reg;
                if (i < 49) {
                    float val = acc[reg] * ((const float*)(lds + RS_B))[i];
                    *(unsigned short*)(lds + OT_B + i * 400 + (h * 32 + dd) * 2) = f2b(val);
                }
            }
        }
        __syncthreads();
    }
#pragma unroll 1
    for (int og = 0; og < 6; ++og) {
        const float* src = proj_w + og * 32 * 192;
        for (int idx = t; idx < 3072; idx += TPB) {
            int ol = idx / 96, c2 = idx - ol * 96;
            float2 v = *(const float2*)(src + ol * 192 + c2 * 2);
            unsigned p = ((unsigned)f2b(v.y) << 16) | (unsigned)f2b(v.x);
            *(unsigned*)(lds + WA_B + ol * 400 + c2 * 4) = p;
        }
        __syncthreads();
        {
            f32x4 acc = {0.f, 0.f, 0.f, 0.f};
            const char* aP = lds + WA_B + (o_l + col) * 400 + 16 * kg;
            const char* bP = lds + OT_B + (n0g + col) * 400 + 16 * kg;
#pragma unroll
            for (int kk = 0; kk < 6; ++kk) {
                bf16x8 a  = *(const bf16x8*)(aP + 64 * kk);
                bf16x8 bb = *(const bf16x8*)(bP + 64 * kk);
                acc = __builtin_amdgcn_mfma_f32_16x16x32_bf16(a, bb, acc, 0, 0, 0);
            }
            const int n = n0g + col;
            if (n < 49) {
                int i = n / 7, j = n - i * 7;
                long base = ((long)(b * 192) * 3136) + (X0 + i) * 56 + (Y0 + j);
#pragma unroll
                for (int reg = 0; reg < 4; ++reg) {
                    int o = og * 32 + o_l + 4 * kg + reg;
                    out[base + (long)o * 3136] = acc[reg] + proj_b[o];
                }
            }
        }
        __syncthreads();
    }
}

extern "C" void kernel_launch(void* const* d_in, const int* in_sizes, int n_in,
                              void* d_out, int out_size, void* d_ws, size_t ws_size,
                              hipStream_t stream) {
    const float* x         = (const float*)d_in[0];
    const float* mask      = (const float*)d_in[1];
    const float* dw_w      = (const float*)d_in[2];
    const float* bn_gamma  = (const float*)d_in[3];
    const float* bn_beta   = (const float*)d_in[4];
    const float* bn_mean   = (const float*)d_in[5];
    const float* bn_var    = (const float*)d_in[6];
    const float* pw_w      = (const float*)d_in[7];
    const float* pw_b      = (const float*)d_in[8];
    const float* proj_w    = (const float*)d_in[9];
    const float* proj_b    = (const float*)d_in[10];
    const float* rel_table = (const float*)d_in[11];
    float* outp            = (float*)d_out;

    const size_t NEED = 192970752ULL;
    if (ws_size >= NEED) {
        char* ws   = (char*)d_ws;
        char* y    = ws;
        char* qkv  = ws + 38535168;
        char* att  = ws + 154140672;
        char* wq   = ws + 192675840;
        char* wp   = ws + 192897024;

        hipLaunchKernelGGL(k0_convert, dim3(288), dim3(256), 0, stream,
                           pw_w, proj_w, (unsigned*)wq, (unsigned*)wp);
        hipLaunchKernelGGL(k1_dwconv, dim3(1792), dim3(256), 0, stream,
                           x, dw_w, bn_gamma, bn_beta, bn_mean, bn_var, (unsigned*)y);
        hipLaunchKernelGGL(k2_qkv, dim3(2352), dim3(512), 0, stream,
                           y, wq, pw_b, qkv);
        hipLaunchKernelGGL(k3_attn, dim3(2048), dim3(512), 0, stream,
                           qkv, mask, rel_table, att);
        hipLaunchKernelGGL(k4_proj, dim3(2352), dim3(512), 0, stream,
                           att, wp, proj_b, outp);
    } else {
        hipLaunchKernelGGL(swin_mfma_kernel, dim3(32 * 64), dim3(512), 0, stream,
                           x, mask, dw_w, bn_gamma, bn_beta, bn_mean, bn_var,
                           pw_w, pw_b, proj_w, proj_b, rel_table, outp);
    }
}

// Round 8
// 346.445 us; speedup vs baseline: 6.9099x; 1.0890x over previous
//
#include <hip/hip_runtime.h>

// Swin window-attention block — 5-kernel pipeline (bf16 MFMA), with fused
// single-kernel fallback when ws_size is insufficient.
//
// ws layout (bytes):
//   Y    @ 0           bf16 [100352][192]   38,535,168
//   QKV  @ 38,535,168  bf16 [100352][576]  115,605,504
//   ATT  @ 154,140,672 bf16 [100352][192]   38,535,168
//   WQ   @ 192,675,840 bf16 [576][192]         221,184
//   WP   @ 192,897,024 bf16 [192][192]          73,728
//   NEED = 192,970,752

typedef __attribute__((ext_vector_type(8))) short bf16x8;
typedef __attribute__((ext_vector_type(4))) float f32x4;
typedef unsigned int uint32;

__device__ __forceinline__ unsigned short f2b(float f) {
    union { float f; unsigned u; } v; v.f = f;
    unsigned r = v.u + 0x7FFFu + ((v.u >> 16) & 1u);   // RNE
    return (unsigned short)(r >> 16);
}

__device__ __forceinline__ void gload_lds16(const void* g, void* l) {
    __builtin_amdgcn_global_load_lds(
        (const __attribute__((address_space(1))) uint32*)g,
        (__attribute__((address_space(3))) uint32*)l, 16, 0, 0);
}

// ---------------- K0: weight fp32 -> bf16 ----------------
__global__ __launch_bounds__(256)
void k0_convert(const float* __restrict__ pw_w, const float* __restrict__ proj_w,
                unsigned* __restrict__ wq, unsigned* __restrict__ wp)
{
    int i = blockIdx.x * 256 + threadIdx.x;              // 73,728 total
    if (i < 55296) {
        float2 v = *(const float2*)(pw_w + 2 * i);
        wq[i] = (unsigned)f2b(v.x) | ((unsigned)f2b(v.y) << 16);
    } else {
        int j = i - 55296;
        float2 v = *(const float2*)(proj_w + 2 * j);
        wp[j] = (unsigned)f2b(v.x) | ((unsigned)f2b(v.y) << 16);
    }
}

// ---------------- K1: depthwise 3x3 + BN -> y[p][192] bf16 ----------------
// One block = (batch, row, 32-ch group). LDS 23,424 B -> 6 blocks/CU (75% occ).
#define K1S 61
__global__ __launch_bounds__(256)
void k1_dwconv(const float* __restrict__ x, const float* __restrict__ dw_w,
               const float* __restrict__ bn_gamma, const float* __restrict__ bn_beta,
               const float* __restrict__ bn_mean, const float* __restrict__ bn_var,
               unsigned* __restrict__ y)                  // bf16 pairs [p][96]
{
    __shared__ float xs[32 * 3 * K1S];                    // [cl][rr][jj], jj=w+1
    const int t = threadIdx.x;
    const int bid = blockIdx.x;
    const int b = bid / 336, rem = bid - b * 336;
    const int r = rem / 6, g = rem - (rem / 6) * 6;
    const int c0 = g * 32;

    // load 32ch x 3 rows x 56 cols (float4), zero-padded rows
#pragma unroll
    for (int it = 0; it < 6; ++it) {
        int item = t + 256 * it;
        if (item < 1344) {                                // 32cl * 3rr * 14(i4)
            int cl = item / 42, rem2 = item - cl * 42;
            int rr = rem2 / 14, i4 = rem2 - rr * 14;
            int r2 = r + rr - 1;
            float4 v = make_float4(0.f, 0.f, 0.f, 0.f);
            if ((unsigned)r2 < 56u)
                v = *(const float4*)(x + ((b * 192 + c0 + cl) * 56 + r2) * 56 + 4 * i4);
            float* dst = &xs[(cl * 3 + rr) * K1S + 1 + 4 * i4];
            dst[0] = v.x; dst[1] = v.y; dst[2] = v.z; dst[3] = v.w;
        }
    }
    if (t < 192) {                                        // zero col pads
        int cl = t / 6, rem2 = t - cl * 6;
        int rr = rem2 >> 1, side = rem2 & 1;
        xs[(cl * 3 + rr) * K1S + (side ? 57 : 0)] = 0.f;
    }
    __syncthreads();

    const int cp = t & 15;                                // channel pair in group
    const int ccq = t >> 4;                               // col quarter base
    const int cA = c0 + 2 * cp, cB = cA + 1;
    float invA = bn_gamma[cA] * rsqrtf(bn_var[cA] + 1e-5f);
    float shA  = bn_beta[cA] - bn_mean[cA] * invA;
    float invB = bn_gamma[cB] * rsqrtf(bn_var[cB] + 1e-5f);
    float shB  = bn_beta[cB] - bn_mean[cB] * invB;
    float wA[9], wB[9];
#pragma unroll
    for (int q = 0; q < 9; ++q) { wA[q] = dw_w[cA * 9 + q]; wB[q] = dw_w[cB * 9 + q]; }
    const float* xa = &xs[(2 * cp) * 3 * K1S];
    const float* xb = &xs[(2 * cp + 1) * 3 * K1S];
#pragma unroll
    for (int it = 0; it < 4; ++it) {
        int cc = ccq + 16 * it;
        if (cc < 56) {
            float a0 = 0.f, a1 = 0.f;
#pragma unroll
            for (int dr = 0; dr < 3; ++dr)
#pragma unroll
                for (int dc = 0; dc < 3; ++dc) {
                    a0 += xa[dr * K1S + cc + dc] * wA[dr * 3 + dc];
                    a1 += xb[dr * K1S + cc + dc] * wB[dr * 3 + dc];
                }
            float y0 = a0 * invA + shA, y1 = a1 * invB + shB;
            int p = b * 3136 + r * 56 + cc;
            y[p * 96 + 16 * g + cp] = (unsigned)f2b(y0) | ((unsigned)f2b(y1) << 16);
        }
    }
}

// ---------------- K2: QKV GEMM [128p x 192o x K192], deferred coalesced epilogue ----
__global__ __launch_bounds__(512, 4)
void k2_qkv(const char* __restrict__ yb, const char* __restrict__ wqb,
            const float* __restrict__ pw_b, char* __restrict__ qkvb)
{
    __shared__ __align__(16) char lds[73728];             // A[128][192] @0, B[64][192] @49152
    int bid = blockIdx.x;
    bid = (bid & 7) * 294 + (bid >> 3);                   // XCD swizzle (2352 = 8*294)
    const int pt = bid / 3, og = bid - (bid / 3) * 3;
    const int p0 = pt * 128;
    const int t = threadIdx.x, lane = t & 63, w = t >> 6;
    const int col = lane & 15, kg = lane >> 4;

    auto stageB = [&](int ot) {
        const char* gB = wqb + (size_t)(ot * 64) * 384;
#pragma unroll
        for (int it = 0; it < 3; ++it) {
            int dl = it * 8192 + w * 1024 + lane * 16;
            int i = dl / 384, c = dl - i * 384;
            gload_lds16(gB + i * 384 + (c ^ ((i & 7) << 4)), lds + 49152 + dl);
        }
    };
    {   // stage A (y rows p0..p0+127) with pre-swizzled source
        const char* gA = yb + (size_t)p0 * 384;
#pragma unroll
        for (int it = 0; it < 6; ++it) {
            int dl = it * 8192 + w * 1024 + lane * 16;
            int i = dl / 384, c = dl - i * 384;
            gload_lds16(gA + i * 384 + (c ^ ((i & 7) << 4)), lds + dl);
        }
        stageB(og * 3);
    }
    __syncthreads();

    const int wp = w & 3, wo = w >> 2;
    const f32x4 zz = {0.f, 0.f, 0.f, 0.f};
    f32x4 acc3[3][2][2];
#pragma unroll
    for (int k = 0; k < 3; ++k) {
#pragma unroll
        for (int mt = 0; mt < 2; ++mt)
#pragma unroll
            for (int nt = 0; nt < 2; ++nt) acc3[k][mt][nt] = zz;
    }
#pragma unroll
    for (int k = 0; k < 3; ++k) {
#pragma unroll
        for (int kk = 0; kk < 6; ++kk) {
            const int c = 16 * kg + 64 * kk;
            bf16x8 a[2], bb[2];
#pragma unroll
            for (int mt = 0; mt < 2; ++mt) {
                int row = 32 * wp + 16 * mt + col;
                a[mt] = *(const bf16x8*)(lds + row * 384 + (c ^ ((row & 7) << 4)));
            }
#pragma unroll
            for (int nt = 0; nt < 2; ++nt) {
                int row = 32 * wo + 16 * nt + col;
                bb[nt] = *(const bf16x8*)(lds + 49152 + row * 384 + (c ^ ((row & 7) << 4)));
            }
#pragma unroll
            for (int mt = 0; mt < 2; ++mt)
#pragma unroll
                for (int nt = 0; nt < 2; ++nt)
                    acc3[k][mt][nt] = __builtin_amdgcn_mfma_f32_16x16x32_bf16(a[mt], bb[nt], acc3[k][mt][nt], 0, 0, 0);
        }
        if (k < 2) {
            __syncthreads();
            stageB(og * 3 + k + 1);
            __syncthreads();
        }
    }
    // ---- deferred epilogue: pack all 192 outputs into dead A region, coalesced store
    __syncthreads();                                      // all A/B reads done
#pragma unroll
    for (int k = 0; k < 3; ++k)
#pragma unroll
        for (int nt = 0; nt < 2; ++nt) {
            int o_l = k * 64 + 32 * wo + 16 * nt + col;    // [0,192)
            float pb = pw_b[og * 192 + o_l];
#pragma unroll
            for (int mt = 0; mt < 2; ++mt)
#pragma unroll
                for (int reg = 0; reg < 4; ++reg) {
                    int p_l = 32 * wp + 16 * mt + 4 * kg + reg;
                    *(unsigned short*)(lds + p_l * 384 +
                        ((2 * o_l) ^ ((p_l & 7) << 4))) = f2b(acc3[k][mt][nt][reg] + pb);
                }
        }
    __syncthreads();
#pragma unroll
    for (int it = 0; it < 6; ++it) {                      // 128 rows x 24 chunks of 16B
        int item = t + 512 * it;
        int p = item / 24, c8 = item - p * 24;
        bf16x8 v = *(const bf16x8*)(lds + p * 384 + ((16 * c8) ^ ((p & 7) << 4)));
        *(bf16x8*)(qkvb + (size_t)(p0 + p) * 1152 + og * 384 + 16 * c8) = v;
    }
}

// ---------------- K3: windowed attention (6 heads), bias fused into dots ----------------
#define QB3    0
#define KB3    19600
#define VTB3   39200
#define EB3    63776
#define DOTS3  70832
#define RS3    81024
#define K3LDS  81220
__global__ __launch_bounds__(512, 4)
void k3_attn(const char* __restrict__ qkvb, const float* __restrict__ mask,
             const float* __restrict__ rel_table, char* __restrict__ attb)
{
    __shared__ __align__(16) char lds[K3LDS];
    const int t = threadIdx.x, lane = t & 63, w = t >> 6;
    const int col = lane & 15, kg = lane >> 4;
    const int b = blockIdx.x >> 6, wid = blockIdx.x & 63;
    const int X0 = (wid >> 3) * 7, Y0 = (wid & 7) * 7;
    const float scale = 0.07216878364870323f;             // 192^-0.5

    auto PIX = [&](int n) { int rr = n / 7; return b * 3136 + (X0 + rr) * 56 + Y0 + (n - rr * 7); };

    // stage Q [49][200ch], K [49][200ch] (stride 400 B)
#pragma unroll
    for (int it = 0; it < 3; ++it) {
        int item = t + 512 * it;
        if (item < 1176) {
            int r = item / 24, c8 = item - r * 24;
            size_t gb = (size_t)PIX(r) * 1152 + 16 * c8;
            *(bf16x8*)(lds + QB3 + r * 400 + 16 * c8) = *(const bf16x8*)(qkvb + gb);
            *(bf16x8*)(lds + KB3 + r * 400 + 16 * c8) = *(const bf16x8*)(qkvb + gb + 384);
        }
    }
    // stage V transposed: VT[192 dd][64 j] (stride 128 B, XOR-swizzled)
#pragma unroll
    for (int it = 0; it < 3; ++it) {
        int item = t + 512 * it;
        if (item < 1176) {
            int j = item / 24, dd8 = item - j * 24;
            bf16x8 v = *(const bf16x8*)(qkvb + (size_t)PIX(j) * 1152 + 768 + 16 * dd8);
            int sw = (dd8 & 7) << 4;
#pragma unroll
            for (int i = 0; i < 8; ++i)
                *(unsigned short*)(lds + VTB3 + (8 * dd8 + i) * 128 + ((2 * j) ^ sw)) =
                    (unsigned short)v[i];
        }
    }
    // zero VT j-pad 49..63
#pragma unroll
    for (int it = 0; it < 6; ++it) {
        int item = t + 512 * it;
        if (item < 2880) {
            int row = item / 15, jz = 49 + (item - (item / 15) * 15);
            *(unsigned short*)(lds + VTB3 + row * 128 + ((2 * jz) ^ (((row >> 3) & 7) << 4))) = 0;
        }
    }
    __syncthreads();

    const int jt = w & 3, ih = w >> 2;                    // dots wave mapping
    const int dd0 = 16 * (w & 1), i0p = 16 * (w >> 1);    // PV wave mapping
    const f32x4 zz = {0.f, 0.f, 0.f, 0.f};

    // hoisted per-lane i-geometry for the two dots q-subtiles
    int iQ[2], aiQ[2], biQ[2];
#pragma unroll
    for (int q = 0; q < 2; ++q) {
        int i = 32 * ih + 16 * q + col;
        iQ[q] = i;
        aiQ[q] = (i * 9363) >> 16;                        // i/7, valid i<64
        biQ[q] = i - aiQ[q] * 7;
    }
    const int j0 = 16 * jt, jb = j0 + 4 * kg;

    for (int h = 0; h < 6; ++h) {
        // ---- dots: D[j][i] = K x Q; fuse scale + rel_bias + mask into epilogue ----
        {
            bf16x8 a = *(const bf16x8*)(lds + KB3 + (j0 + col) * 400 + 64 * h + 16 * kg);
#pragma unroll
            for (int q = 0; q < 2; ++q) {
                int i0 = 32 * ih + 16 * q;
                bf16x8 bb = *(const bf16x8*)(lds + QB3 + (i0 + col) * 400 + 64 * h + 16 * kg);
                f32x4 d4 = __builtin_amdgcn_mfma_f32_16x16x32_bf16(a, bb, zz, 0, 0, 0);
                int i = iQ[q];
                if (i < 49 && jb <= 48) {
                    const float* mrow = mask + (wid * 49 + i) * 49;
                    const int ai = aiQ[q], bi = biQ[q];
                    if (jb < 48) {                         // all 4 j valid (jb<=44)
                        float4 mk = *(const float4*)(mrow + jb);
#pragma unroll
                        for (int reg = 0; reg < 4; ++reg) {
                            int j = jb + reg;
                            int aj = (j * 9363) >> 16, bj = j - aj * 7;
                            int ridx = (ai - aj + 6) * 13 + (bi - bj + 6);
                            d4[reg] = d4[reg] * scale + rel_table[ridx * 6 + h]
                                    + (&mk.x)[reg];
                        }
                    } else {                               // jb==48: only j=48 valid
                        int ridx = ai * 13 + bi;           // aj=bj=6
                        d4[0] = d4[0] * scale + rel_table[ridx * 6 + h] + mrow[48];
                    }
                    *(f32x4*)(lds + DOTS3 + (i * 52 + jb) * 4) = d4;
                }
            }
        }
        __syncthreads();
        // ---- softmax (pure max/exp/sum), E bf16 [49][72ch], RS=1/sum ----
        if (t < 392) {
            int r = t >> 3, j8 = t & 7;
            const float* drow = (const float*)(lds + DOTS3) + r * 52;
            float mx = -3.4e38f;
            for (int j = j8; j < 49; j += 8) mx = fmaxf(mx, drow[j]);
            mx = fmaxf(mx, __shfl_xor(mx, 1));
            mx = fmaxf(mx, __shfl_xor(mx, 2));
            mx = fmaxf(mx, __shfl_xor(mx, 4));
            float s = 0.f;
            for (int j = j8; j < 49; j += 8) {
                float e = __expf(drow[j] - mx);
                s += e;
                *(unsigned short*)(lds + EB3 + r * 144 + 2 * j) = f2b(e);
            }
            *(unsigned short*)(lds + EB3 + r * 144 + 2 * (49 + j8)) = 0;
            if (57 + j8 < 64)
                *(unsigned short*)(lds + EB3 + r * 144 + 2 * (57 + j8)) = 0;
            s += __shfl_xor(s, 1);
            s += __shfl_xor(s, 2);
            s += __shfl_xor(s, 4);
            if (j8 == 0) ((float*)(lds + RS3))[r] = 1.f / s;
        }
        __syncthreads();
        // ---- PV: D[dd][i] = VT x E ; packed 8-B stores ----
        {
            f32x4 acc = zz;
            const int ddg = h * 32 + dd0 + col;
#pragma unroll
            for (int kk = 0; kk < 2; ++kk) {
                bf16x8 a = *(const bf16x8*)(lds + VTB3 + ddg * 128 +
                               ((16 * kg + 64 * kk) ^ (((ddg >> 3) & 7) << 4)));
                bf16x8 bb = *(const bf16x8*)(lds + EB3 + (i0p + col) * 144 + 16 * kg + 64 * kk);
                acc = __builtin_amdgcn_mfma_f32_16x16x32_bf16(a, bb, acc, 0, 0, 0);
            }
            int i = i0p + col;
            if (i < 49) {
                float rs = ((const float*)(lds + RS3))[i];
                unsigned u0 = (unsigned)f2b(acc[0] * rs) | ((unsigned)f2b(acc[1] * rs) << 16);
                unsigned u1 = (unsigned)f2b(acc[2] * rs) | ((unsigned)f2b(acc[3] * rs) << 16);
                *(uint2*)(attb + ((size_t)PIX(i) * 192 + h * 32 + dd0 + 4 * kg) * 2) =
                    make_uint2(u0, u1);
            }
        }
        // no barrier needed here (DOTS region disjoint from E/RS; post-dots
        // barrier orders all PV reads of E before softmax overwrites it)
    }
}

// ---------------- K4: proj GEMM -> fp32 NCHW out ----------------
__global__ __launch_bounds__(512, 4)
void k4_proj(const char* __restrict__ attb, const char* __restrict__ wpb,
             const float* __restrict__ proj_b, float* __restrict__ outp)
{
    __shared__ __align__(16) char lds[73728];             // W[64][192] @0, X[128][192] @24576
    int bid = blockIdx.x;
    bid = (bid & 7) * 294 + (bid >> 3);                   // 2352 = 8*294
    const int pt = bid / 3, ot = bid - (bid / 3) * 3;
    const int p0 = pt * 128, o0 = ot * 64;
    const int t = threadIdx.x, lane = t & 63, w = t >> 6;
    const int col = lane & 15, kg = lane >> 4;

    {
        const char* gW = wpb + (size_t)o0 * 384;
        const char* gX = attb + (size_t)p0 * 384;
#pragma unroll
        for (int it = 0; it < 9; ++it) {
            int d = it * 8192 + w * 1024 + lane * 16;
            int dl = (it < 3) ? d : d - 24576;
            const char* gb = (it < 3) ? gW : gX;
            int i = dl / 384, c = dl - i * 384;
            gload_lds16(gb + i * 384 + (c ^ ((i & 7) << 4)), lds + d);
        }
    }
    __syncthreads();

    const int wo = w & 1, wp4 = w >> 1;
    const f32x4 zz = {0.f, 0.f, 0.f, 0.f};
    f32x4 acc[2][2];
    acc[0][0] = zz; acc[0][1] = zz; acc[1][0] = zz; acc[1][1] = zz;
#pragma unroll
    for (int kk = 0; kk < 6; ++kk) {
        const int c = 16 * kg + 64 * kk;
        bf16x8 a[2], bb[2];
#pragma unroll
        for (int mt = 0; mt < 2; ++mt) {
            int row = 32 * wo + 16 * mt + col;
            a[mt] = *(const bf16x8*)(lds + row * 384 + (c ^ ((row & 7) << 4)));
        }
#pragma unroll
        for (int nt = 0; nt < 2; ++nt) {
            int row = 32 * wp4 + 16 * nt + col;
            bb[nt] = *(const bf16x8*)(lds + 24576 + row * 384 + (c ^ ((row & 7) << 4)));
        }
#pragma unroll
        for (int mt = 0; mt < 2; ++mt)
#pragma unroll
            for (int nt = 0; nt < 2; ++nt)
                acc[mt][nt] = __builtin_amdgcn_mfma_f32_16x16x32_bf16(a[mt], bb[nt], acc[mt][nt], 0, 0, 0);
    }
#pragma unroll
    for (int nt = 0; nt < 2; ++nt) {
        int p_g = p0 + 32 * wp4 + 16 * nt + col;
        int bg = p_g / 3136, hw = p_g - bg * 3136;
#pragma unroll
        for (int mt = 0; mt < 2; ++mt)
#pragma unroll
            for (int reg = 0; reg < 4; ++reg) {
                int o_g = o0 + 32 * wo + 16 * mt + 4 * kg + reg;
                outp[(size_t)(bg * 192 + o_g) * 3136 + hw] = acc[mt][nt][reg] + proj_b[o_g];
            }
    }
}

// ================= fallback: round-2 fused kernel (passes, 617 us) =================
#define TPB 512
#define OT_B   0
#define YT_B   20800
#define WA_B   41600
#define QS_B   54400
#define KS_B   58560
#define VT_B   62720
#define E_B    67328
#define LDS_TOTAL 76480
#define DOTS_B WA_B
#define RS_B   (WA_B + 10192)
#define XS_B   WA_B
#define DWL_B  OT_B
#define SC_B   (OT_B + 3456)
#define SH_B   (OT_B + 4224)

__global__ __launch_bounds__(TPB, 4)
void swin_mfma_kernel(const float* __restrict__ x,
                      const float* __restrict__ mask,
                      const float* __restrict__ dw_w,
                      const float* __restrict__ bn_gamma,
                      const float* __restrict__ bn_beta,
                      const float* __restrict__ bn_mean,
                      const float* __restrict__ bn_var,
                      const float* __restrict__ pw_w,
                      const float* __restrict__ pw_b,
                      const float* __restrict__ proj_w,
                      const float* __restrict__ proj_b,
                      const float* __restrict__ rel_table,
                      float* __restrict__ out)
{
    __shared__ __align__(16) char lds[LDS_TOTAL];
    const int t    = threadIdx.x;
    const int blk  = blockIdx.x;
    const int b    = blk >> 6;
    const int wid  = blk & 63;
    const int X0   = (wid >> 3) * 7, Y0 = (wid & 7) * 7;
    const int lane = t & 63;
    const int w    = t >> 6;
    const int col  = lane & 15;
    const int kg   = lane >> 4;
    const float scale = 0.07216878364870323f;

    if (t < 192) {
        float inv = bn_gamma[t] * rsqrtf(bn_var[t] + 1e-5f);
        ((float*)(lds + SC_B))[t] = inv;
        ((float*)(lds + SH_B))[t] = bn_beta[t] - bn_mean[t] * inv;
    }
    for (int half = 0; half < 2; ++half) {
        const int c0 = half * 96;
        for (int idx = t; idx < 96 * 9; idx += TPB)
            ((float*)(lds + DWL_B))[idx] = dw_w[c0 * 9 + idx];
        for (int idx = t; idx < 96 * 81; idx += TPB) {
            int cl = idx / 81, p = idx - cl * 81;
            int di = p / 9, dj = p - di * 9;
            int r = X0 - 1 + di, cc = Y0 - 1 + dj;
            float v = 0.f;
            if ((unsigned)r < 56u && (unsigned)cc < 56u)
                v = x[((b * 192 + c0 + cl) * 56 + r) * 56 + cc];
            ((float*)(lds + XS_B))[cl * 84 + p] = v;
        }
        __syncthreads();
        for (int idx = t; idx < 96 * 49; idx += TPB) {
            int cl = idx / 49, n = idx - cl * 49;
            int i = n / 7, j = n - i * 7;
            const float* xc = (const float*)(lds + XS_B) + cl * 84;
            const float* wl = (const float*)(lds + DWL_B) + cl * 9;
            float acc = 0.f;
#pragma unroll
            for (int dr = 0; dr < 3; ++dr)
#pragma unroll
                for (int ds = 0; ds < 3; ++ds)
                    acc += xc[(i + dr) * 9 + (j + ds)] * wl[dr * 3 + ds];
            int c = c0 + cl;
            float yv = acc * ((float*)(lds + SC_B))[c] + ((float*)(lds + SH_B))[c];
            *(unsigned short*)(lds + YT_B + n * 400 + c * 2) = f2b(yv);
        }
        __syncthreads();
    }
    const int o_l = 16 * (w & 1);
    const int n0g = 16 * (w >> 1);
    for (int h = 0; h < 6; ++h) {
#pragma unroll 1
        for (int m = 0; m < 3; ++m) {
            const int o_base = m * 192 + h * 32;
            const float* src = pw_w + o_base * 192;
            for (int idx = t; idx < 3072; idx += TPB) {
                int ol = idx / 96, c2 = idx - ol * 96;
                float2 v = *(const float2*)(src + ol * 192 + c2 * 2);
                unsigned p = ((unsigned)f2b(v.y) << 16) | (unsigned)f2b(v.x);
                *(unsigned*)(lds + WA_B + ol * 400 + c2 * 4) = p;
            }
            __syncthreads();
            {
                f32x4 acc = {0.f, 0.f, 0.f, 0.f};
                const char* aP = lds + WA_B + (o_l + col) * 400 + 16 * kg;
                const char* bP = lds + YT_B + (n0g + col) * 400 + 16 * kg;
#pragma unroll
                for (int kk = 0; kk < 6; ++kk) {
                    bf16x8 a  = *(const bf16x8*)(aP + 64 * kk);
                    bf16x8 bb = *(const bf16x8*)(bP + 64 * kk);
                    acc = __builtin_amdgcn_mfma_f32_16x16x32_bf16(a, bb, acc, 0, 0, 0);
                }
                const int n = n0g + col;
#pragma unroll
                for (int reg = 0; reg < 4; ++reg) {
                    int od = o_l + 4 * kg + reg;
                    float val = acc[reg] + pw_b[o_base + od];
                    if (m == 2) {
                        *(unsigned short*)(lds + VT_B + od * 144 + n * 2) =
                            f2b(n < 49 ? val : 0.f);
                    } else if (n < 49) {
                        int dst = (m == 0 ? QS_B : KS_B);
                        *(unsigned short*)(lds + dst + n * 80 + od * 2) = f2b(val);
                    }
                }
            }
            __syncthreads();
        }
        {
            const int i0 = 16 * (w & 3);
            const int jp = w >> 2;
            bf16x8 a = *(const bf16x8*)(lds + QS_B + (i0 + col) * 80 + 16 * kg);
            f32x4 acc[2];
#pragma unroll
            for (int jt = 0; jt < 2; ++jt) {
                int j0 = 32 * jp + 16 * jt;
                bf16x8 bb = *(const bf16x8*)(lds + KS_B + (j0 + col) * 80 + 16 * kg);
                f32x4 z = {0.f, 0.f, 0.f, 0.f};
                acc[jt] = __builtin_amdgcn_mfma_f32_16x16x32_bf16(a, bb, z, 0, 0, 0);
            }
#pragma unroll
            for (int jt = 0; jt < 2; ++jt) {
                int j = 32 * jp + 16 * jt + col;
                if (j < 49) {
                    int aj = (j * 9363) >> 16, bj = j - aj * 7;
#pragma unroll
                    for (int reg = 0; reg < 4; ++reg) {
                        int i = i0 + 4 * kg + reg;
                        if (i < 49) {
                            int ai = (i * 9363) >> 16, bi = i - ai * 7;
                            int ridx = (ai - aj + 6) * 13 + (bi - bj + 6);
                            float val = acc[jt][reg] * scale
                                      + rel_table[ridx * 6 + h]
                                      + mask[wid * 2401 + i * 49 + j];
                            *(float*)(lds + DOTS_B + (i * 52 + j) * 4) = val;
                        }
                    }
                }
            }
        }
        __syncthreads();
        if (t < 392) {
            const int r = t >> 3, j8 = t & 7;
            const float* drow = (const float*)(lds + DOTS_B) + r * 52;
            float mx = -3.4e38f;
            for (int j = j8; j < 49; j += 8) mx = fmaxf(mx, drow[j]);
            mx = fmaxf(mx, __shfl_xor(mx, 1));
            mx = fmaxf(mx, __shfl_xor(mx, 2));
            mx = fmaxf(mx, __shfl_xor(mx, 4));
            float s = 0.f;
            for (int j = j8; j < 49; j += 8) {
                float e = __expf(drow[j] - mx);
                s += e;
                *(unsigned short*)(lds + E_B + r * 144 + j * 2) = f2b(e);
            }
            *(unsigned short*)(lds + E_B + r * 144 + (49 + j8) * 2) = 0;
            if (57 + j8 < 64)
                *(unsigned short*)(lds + E_B + r * 144 + (57 + j8) * 2) = 0;
            s += __shfl_xor(s, 1);
            s += __shfl_xor(s, 2);
            s += __shfl_xor(s, 4);
            if (j8 == 0) ((float*)(lds + RS_B))[r] = 1.f / s;
        }
        __syncthreads();
        {
            const int i0  = 16 * (w & 3);
            const int dd0 = 16 * (w >> 2);
            f32x4 acc = {0.f, 0.f, 0.f, 0.f};
#pragma unroll
            for (int kk = 0; kk < 2; ++kk) {
                bf16x8 a  = *(const bf16x8*)(lds + E_B  + (i0 + col) * 144 + 64 * kk + 16 * kg);
                bf16x8 bb = *(const bf16x8*)(lds + VT_B + (dd0 + col) * 144 + 64 * kk + 16 * kg);
                acc = __builtin_amdgcn_mfma_f32_16x16x32_bf16(a, bb, acc, 0, 0, 0);
            }
            const int dd = dd0 + col;
#pragma unroll
            for (int reg = 0; reg < 4; ++reg) {
                int i = i0 + 4 * kg + reg;
                if (i < 49) {
                    float val = acc[reg] * ((const float*)(lds + RS_B))[i];
                    *(unsigned short*)(lds + OT_B + i * 400 + (h * 32 + dd) * 2) = f2b(val);
                }
            }
        }
        __syncthreads();
    }
#pragma unroll 1
    for (int og = 0; og < 6; ++og) {
        const float* src = proj_w + og * 32 * 192;
        for (int idx = t; idx < 3072; idx += TPB) {
            int ol = idx / 96, c2 = idx - ol * 96;
            float2 v = *(const float2*)(src + ol * 192 + c2 * 2);
            unsigned p = ((unsigned)f2b(v.y) << 16) | (unsigned)f2b(v.x);
            *(unsigned*)(lds + WA_B + ol * 400 + c2 * 4) = p;
        }
        __syncthreads();
        {
            f32x4 acc = {0.f, 0.f, 0.f, 0.f};
            const char* aP = lds + WA_B + (o_l + col) * 400 + 16 * kg;
            const char* bP = lds + OT_B + (n0g + col) * 400 + 16 * kg;
#pragma unroll
            for (int kk = 0; kk < 6; ++kk) {
                bf16x8 a  = *(const bf16x8*)(aP + 64 * kk);
                bf16x8 bb = *(const bf16x8*)(bP + 64 * kk);
                acc = __builtin_amdgcn_mfma_f32_16x16x32_bf16(a, bb, acc, 0, 0, 0);
            }
            const int n = n0g + col;
            if (n < 49) {
                int i = n / 7, j = n - i * 7;
                long base = ((long)(b * 192) * 3136) + (X0 + i) * 56 + (Y0 + j);
#pragma unroll
                for (int reg = 0; reg < 4; ++reg) {
                    int o = og * 32 + o_l + 4 * kg + reg;
                    out[base + (long)o * 3136] = acc[reg] + proj_b[o];
                }
            }
        }
        __syncthreads();
    }
}

extern "C" void kernel_launch(void* const* d_in, const int* in_sizes, int n_in,
                              void* d_out, int out_size, void* d_ws, size_t ws_size,
                              hipStream_t stream) {
    const float* x         = (const float*)d_in[0];
    const float* mask      = (const float*)d_in[1];
    const float* dw_w      = (const float*)d_in[2];
    const float* bn_gamma  = (const float*)d_in[3];
    const float* bn_beta   = (const float*)d_in[4];
    const float* bn_mean   = (const float*)d_in[5];
    const float* bn_var    = (const float*)d_in[6];
    const float* pw_w      = (const float*)d_in[7];
    const float* pw_b      = (const float*)d_in[8];
    const float* proj_w    = (const float*)d_in[9];
    const float* proj_b    = (const float*)d_in[10];
    const float* rel_table = (const float*)d_in[11];
    float* outp            = (float*)d_out;

    const size_t NEED = 192970752ULL;
    if (ws_size >= NEED) {
        char* ws   = (char*)d_ws;
        char* y    = ws;
        char* qkv  = ws + 38535168;
        char* att  = ws + 154140672;
        char* wq   = ws + 192675840;
        char* wp   = ws + 192897024;

        hipLaunchKernelGGL(k0_convert, dim3(288), dim3(256), 0, stream,
                           pw_w, proj_w, (unsigned*)wq, (unsigned*)wp);
        hipLaunchKernelGGL(k1_dwconv, dim3(32 * 56 * 6), dim3(256), 0, stream,
                           x, dw_w, bn_gamma, bn_beta, bn_mean, bn_var, (unsigned*)y);
        hipLaunchKernelGGL(k2_qkv, dim3(2352), dim3(512), 0, stream,
                           y, wq, pw_b, qkv);
        hipLaunchKernelGGL(k3_attn, dim3(2048), dim3(512), 0, stream,
                           qkv, mask, rel_table, att);
        hipLaunchKernelGGL(k4_proj, dim3(2352), dim3(512), 0, stream,
                           att, wp, proj_b, outp);
    } else {
        hipLaunchKernelGGL(swin_mfma_kernel, dim3(32 * 64), dim3(512), 0, stream,
                           x, mask, dw_w, bn_gamma, bn_beta, bn_mean, bn_var,
                           pw_w, pw_b, proj_w, proj_b, rel_table, outp);
    }
}